// Round 1
// baseline (72.154 us; speedup 1.0000x reference)
//
#include <hip/hip_runtime.h>

// CollisionLoss: pos [65536, 24, 3] fp32 -> scalar.
// Static mask: point 0 excluded, pair (2,3) excluded, diagonal excluded.
// Symmetric mask => evaluate only i<j pairs (252); num and denom both halve,
// ratio unchanged. dist<0.5 <=> sq<0.25; exp(-(dist/0.5)^2) = exp(-4*sq)
// = exp2(sq * -4/ln2) => no sqrt, and v_exp_f32 fed directly.
// This version: 4 waves/block (4 waves/SIMD occupancy), rows LPT-split 63/63/63/63
// across waves, packed-fp32 (v_pk_*) pair math: 2 pairs per packed op.

#define NPTS 24
#define BLK 256          // 4 waves; each wave owns a 63-pair row set
#define BATCHES_PER_BLK 64
#define LDS_STRIDE 73    // 73 mod 32 = 9 (odd) -> 2 lanes/bank on reads (free)

typedef float v2f __attribute__((ext_vector_type(2)));

struct Pts {
    v2f x[12], y[12], z[12];   // component g = points {2g, 2g+1}
};

#define EXP2_SCALE (-5.770780163555852f)   /* -4/ln(2) */

// Process row I (pairs (I,j) for j in jstart..23), jstart = I+1 except row 2
// which starts at 4 (pair (2,3) excluded). Packed: 2 pairs per v_pk op.
template<int I>
__device__ __forceinline__ void row(const Pts& p, v2f& acc, int& cc) {
    constexpr int JS = (I == 2) ? 4 : (I + 1);
    constexpr int H = I >> 1;
    constexpr int L = I & 1;
    const float xi = L ? p.x[H].y : p.x[H].x;
    const float yi = L ? p.y[H].y : p.y[H].x;
    const float zi = L ? p.z[H].y : p.z[H].x;

    if constexpr (JS & 1) {          // odd start -> one scalar pair (I, JS)
        constexpr int JH = JS >> 1;  // JS odd -> .y component
        float dx = xi - p.x[JH].y;
        float dy = yi - p.y[JH].y;
        float dz = zi - p.z[JH].y;
        float sq = fmaf(dx, dx, fmaf(dy, dy, dz * dz));
        bool  w  = sq < 0.25f;
        cc += (int)__popcll(__ballot(w));
        float e = __builtin_amdgcn_exp2f(sq * EXP2_SCALE);
        acc.x += w ? e : 0.0f;
    }

    constexpr int G0 = (JS + 1) >> 1;   // first full {2g,2g+1} group
    const v2f xiv = {xi, xi}, yiv = {yi, yi}, ziv = {zi, zi};
    #pragma unroll
    for (int g = G0; g < 12; ++g) {
        v2f dx = xiv - p.x[g];
        v2f dy = yiv - p.y[g];
        v2f dz = ziv - p.z[g];
        v2f sq = __builtin_elementwise_fma(dx, dx,
                 __builtin_elementwise_fma(dy, dy, dz * dz));
        v2f m  = sq * (v2f){EXP2_SCALE, EXP2_SCALE};
        bool w0 = sq.x < 0.25f;
        bool w1 = sq.y < 0.25f;
        cc += (int)__popcll(__ballot(w0));
        cc += (int)__popcll(__ballot(w1));
        float e0 = __builtin_amdgcn_exp2f(m.x);
        float e1 = __builtin_amdgcn_exp2f(m.y);
        acc += (v2f){ w0 ? e0 : 0.0f, w1 ? e1 : 0.0f };
    }
}

__global__ __launch_bounds__(BLK, 4)
void collision_main(const float* __restrict__ pos, float2* __restrict__ ws) {
    __shared__ float lds[BATCHES_PER_BLK * LDS_STRIDE];
    const int t = threadIdx.x;                        // 0..255
    const int blockBase = blockIdx.x * BATCHES_PER_BLK;

    // --- Stage 64 batches * 72 floats = 1152 float4, coalesced ---
    const float4* gp = (const float4*)pos + (size_t)blockBase * 18; // 18 f4/batch
    #pragma unroll
    for (int k = 0; k < 5; ++k) {
        int f4 = t + k * BLK;                 // 0..1279; valid < 1152
        if (f4 < 1152) {
            float4 v = gp[f4];
            int b  = f4 / 18;
            int e4 = f4 % 18;
            float* dst = &lds[b * LDS_STRIDE + e4 * 4];
            dst[0] = v.x; dst[1] = v.y; dst[2] = v.z; dst[3] = v.w;
        }
    }
    __syncthreads();

    // --- Each thread owns batch (t & 63); 4 waves each take 63 of 252 pairs ---
    Pts p;
    const float* src = &lds[(t & 63) * LDS_STRIDE];
    #pragma unroll
    for (int g = 0; g < 12; ++g) {
        p.x[g] = (v2f){src[6 * g + 0], src[6 * g + 3]};
        p.y[g] = (v2f){src[6 * g + 1], src[6 * g + 4]};
        p.z[g] = (v2f){src[6 * g + 2], src[6 * g + 5]};
    }

    v2f acc = {0.0f, 0.0f};
    int cc = 0;                 // wave-uniform collision count via ballot
    const int q = t >> 6;       // wave id -> LPT-balanced row set (63 pairs each)
    if (q == 0) {
        row< 1>(p, acc, cc); row< 8>(p, acc, cc); row<10>(p, acc, cc);
        row<15>(p, acc, cc); row<18>(p, acc, cc);
    } else if (q == 1) {
        row< 2>(p, acc, cc); row< 6>(p, acc, cc); row<11>(p, acc, cc);
        row<14>(p, acc, cc); row<19>(p, acc, cc); row<22>(p, acc, cc);
    } else if (q == 2) {
        row< 3>(p, acc, cc); row< 7>(p, acc, cc); row< 9>(p, acc, cc);
        row<16>(p, acc, cc); row<17>(p, acc, cc);
    } else {
        row< 4>(p, acc, cc); row< 5>(p, acc, cc); row<12>(p, acc, cc);
        row<13>(p, acc, cc); row<20>(p, acc, cc); row<21>(p, acc, cc);
    }

    // --- Wave reduce s; cc is already wave-uniform ---
    float s = acc.x + acc.y;
    #pragma unroll
    for (int off = 32; off >= 1; off >>= 1)
        s += __shfl_down(s, off, 64);

    __shared__ float sred[4];
    __shared__ int   cred[4];
    if ((t & 63) == 0) { sred[q] = s; cred[q] = cc; }
    __syncthreads();
    if (t == 0) {
        float2 pr;
        pr.x = sred[0] + sred[1] + sred[2] + sred[3];
        pr.y = (float)(cred[0] + cred[1] + cred[2] + cred[3]); // <=16128, exact
        ws[blockIdx.x] = pr;                 // overwrite: no init needed
    }
}

__global__ __launch_bounds__(256)
void collision_reduce(const float* __restrict__ ws, float* __restrict__ out) {
    // 1024 float2 partials = 512 float4; 2 float4 per thread
    const float4* p4 = (const float4*)ws;
    const int t = threadIdx.x;
    float s = 0.0f, c = 0.0f;
    #pragma unroll
    for (int k = 0; k < 2; ++k) {
        float4 v = p4[t + k * 256];
        s += v.x + v.z;
        c += v.y + v.w;
    }
    #pragma unroll
    for (int off = 32; off >= 1; off >>= 1) {
        s += __shfl_down(s, off, 64);
        c += __shfl_down(c, off, 64);
    }
    __shared__ float sb[4], cb[4];
    if ((t & 63) == 0) { sb[t >> 6] = s; cb[t >> 6] = c; }
    __syncthreads();
    if (t == 0) {
        s = sb[0] + sb[1] + sb[2] + sb[3];
        c = cb[0] + cb[1] + cb[2] + cb[3];
        float total = (c > 0.0f) ? (s / fmaxf(c, 1.0f)) : 0.0f;
        out[0] = total + 1e-6f;
    }
}

extern "C" void kernel_launch(void* const* d_in, const int* in_sizes, int n_in,
                              void* d_out, int out_size, void* d_ws, size_t ws_size,
                              hipStream_t stream) {
    const float* pos = (const float*)d_in[0];
    float* out = (float*)d_out;
    float2* ws = (float2*)d_ws;

    const int B = in_sizes[0] / (NPTS * 3);   // 65536
    const int nblocks = B / BATCHES_PER_BLK;  // 1024

    collision_main<<<nblocks, BLK, 0, stream>>>(pos, ws);
    collision_reduce<<<1, 256, 0, stream>>>((const float*)ws, out);
}